// Round 10
// baseline (476.124 us; speedup 1.0000x reference)
//
#include <hip/hip_runtime.h>
#include <stdint.h>

#define BDIM    1024                  // 16 waves per batch
#define NROWS   32
#define CDIM    1024
#define NSTEPS  31
#define BATCH   512

// One 1024-thread block (16 waves) per batch. ALL alive rows in REGISTERS:
// wave w owns 2 "banks" R[0..1] = slots 2w,2w+1; lane holds elements
// [lane*16 .. lane*16+15]. Merged row overwrites slot sb's bank and D-row
// (slot idx[bb] provably dead after every merge). The OTHER dead slot is
// idx[a] normally but idx[0] when a==1 (reference quirk: x[1] is both merged
// and survives at position bb; x[0] is dropped). Argmin DISTRIBUTED: one
// flat candidate per thread (n^2 <= 1024), per-wave butterfly -> 16 LDS
// partials -> every wave combines locally after B1 (same (fp64 d2, flat)
// lexicographic key = reference order). 3 barriers/step. No global reads
// after init. __launch_bounds__(1024,8) caps VGPR at 64 so 2 blocks/CU
// (32 waves/CU) co-schedule.
__global__ __launch_bounds__(BDIM, 8)
void merge_tree_kernel(const float* __restrict__ xin,  // B*32*1024 fp32
                       const float* __restrict__ wz,   // 6 fp32 (1,2,3)
                       const float* __restrict__ bz,   // 1 fp32
                       float* __restrict__ out)        // B*1024 fp32
{
    const int b    = blockIdx.x;
    const int tid  = threadIdx.x;
    const int lane = tid & 63;
    const int wid  = tid >> 6;        // 0..15

    const float* xb = xin + (size_t)b * NROWS * CDIM;

    __shared__ double D[NROWS][NROWS + 1];   // slot-indexed d2 (8448 B)
    __shared__ float  mA[16 * 64];           // conv partial (ch0), [e][lane]
    __shared__ float  mB[16 * 64];           // conv partial (ch1), [e][lane]
    __shared__ int    idxbuf[2][NROWS];      // logical pos -> slot
    __shared__ int    bankSlot[NROWS];       // bank (wid*2+k) -> slot, -1 dead
    __shared__ double wredv[16];             // per-wave argmin partial keys
    __shared__ int    wredp[16];             // per-wave argmin partial flats

    const float w00 = wz[0], w01 = wz[1], w02 = wz[2];
    const float w10 = wz[3], w11 = wz[4], w12 = wz[5];
    const float cb  = bz[0];

    float R[2][16];                   // 2 owned rows (32 VGPRs)
    float m[16];                      // current merged row / temp

    // ---------- load own rows (one-time) ----------
    #pragma unroll
    for (int k = 0; k < 2; k++) {
        const float4* src = (const float4*)(xb + (size_t)(2 * wid + k) * CDIM);
        #pragma unroll
        for (int q = 0; q < 4; q++) {
            float4 t = src[lane * 4 + q];
            R[k][4*q] = t.x; R[k][4*q+1] = t.y; R[k][4*q+2] = t.z; R[k][4*q+3] = t.w;
        }
    }
    if (tid < NROWS) { idxbuf[0][tid] = tid; bankSlot[tid] = tid; }

    // ---------- init pairwise D: stream row i, dist vs own banks ----------
    for (int i = 0; i < NROWS - 1; i++) {
        const float4* src = (const float4*)(xb + (size_t)i * CDIM);
        #pragma unroll
        for (int q = 0; q < 4; q++) {
            float4 t = src[lane * 4 + q];
            m[4*q] = t.x; m[4*q+1] = t.y; m[4*q+2] = t.z; m[4*q+3] = t.w;
        }
        #pragma unroll
        for (int k = 0; k < 2; k++) {
            const int s = 2 * wid + k;
            if (s > i) {              // wave-uniform
                double acc = 0.0;
                #pragma unroll
                for (int e = 0; e < 16; e++) {
                    float d = m[e] - R[k][e];
                    acc += (double)d * (double)d;
                }
                #pragma unroll
                for (int off = 32; off > 0; off >>= 1) acc += __shfl_down(acc, off, 64);
                if (lane == 0) { D[i][s] = acc; D[s][i] = acc; }
            }
        }
    }
    __syncthreads();

    // ---------- main merge loop: 3 barriers/step ----------
    int p = 0;
    for (int step = 0; step < NSTEPS; step++) {
        const int n = NROWS - step;
        int* idx  = idxbuf[p];
        int* nidx = idxbuf[p ^ 1];

        // --- argmin, distributed: one flat candidate per thread ---
        const uint32_t M = 0xFFFFFFFFu / (uint32_t)n + 1u;  // exact for flat<2^27
        {
            double bk = 1e300; int bp = 0x7fffffff;
            const int flat = tid;
            if (flat < n * n) {
                int i = (int)__umulhi((uint32_t)flat, M);
                int j = flat - i * n;
                if (j > i) { bk = D[idx[i]][idx[j]]; bp = flat; }
            }
            #pragma unroll
            for (int off = 1; off < 64; off <<= 1) {
                double ov = __shfl_xor(bk, off); int op = __shfl_xor(bp, off);
                if (ov < bk || (ov == bk && op < bp)) { bk = ov; bp = op; }
            }
            if (lane == 0) { wredv[wid] = bk; wredp[wid] = bp; }
        }
        __syncthreads();                                   // B1

        // combine 16 partials (every wave, redundant, no extra barrier)
        int a, bbj;
        {
            double v = (lane < 16) ? wredv[lane] : 1e300;
            int    q = (lane < 16) ? wredp[lane] : 0x7fffffff;
            #pragma unroll
            for (int off = 1; off < 16; off <<= 1) {
                double ov = __shfl_xor(v, off); int oq = __shfl_xor(q, off);
                if (ov < v || (ov == v && oq < q)) { v = ov; q = oq; }
            }
            const int best = __shfl(q, 0, 64);
            a   = (int)__umulhi((uint32_t)best, M);
            bbj = best - a * n;
        }
        const int sa = idx[a], sb = idx[bbj];
        // dead slots: sb (always) and idx[a] — except a==1 drops idx[0]
        const int deadSlot = (a == 1) ? idx[0] : sa;

        // --- conv partials by owner waves, from registers, into [e][lane] LDS ---
        #pragma unroll
        for (int k = 0; k < 2; k++) {
            const int s = bankSlot[wid * 2 + k];           // wave-uniform
            if (s == sa || s == sb) {
                float hl = __shfl_up(R[k][15], 1);  if (lane == 0)  hl = 0.0f;
                float hr = __shfl_down(R[k][0], 1); if (lane == 63) hr = 0.0f;
                float* dst = (s == sa) ? mA : mB;
                const float c0 = (s == sa) ? w00 : w10;
                const float c1 = (s == sa) ? w01 : w11;
                const float c2 = (s == sa) ? w02 : w12;
                #pragma unroll
                for (int e = 0; e < 16; e++) {
                    float xm1 = (e == 0)  ? hl : R[k][e - 1];
                    float xp1 = (e == 15) ? hr : R[k][e + 1];
                    dst[e * 64 + lane] = c0 * xm1 + c1 * R[k][e] + c2 * xp1;
                }
            }
        }
        // bookkeeping: new logical order (merged keeps slot id sb)
        if (tid == 0) nidx[0] = sb;
        if (tid >= 1 && tid < n - 1) {
            int kk = tid + 1;
            int src = (kk == bbj) ? 1 : ((kk == a) ? 0 : kk);
            nidx[tid] = idx[src];
        }
        __syncthreads();                                   // B2

        // --- finalize m (all waves); conflict-free strided reads ---
        #pragma unroll
        for (int e = 0; e < 16; e++) {
            float v = cb + mA[e * 64 + lane] + mB[e * 64 + lane];
            m[e] = v > 0.0f ? v : 0.0f;
        }
        // owner(sb): bank <- m; owner(deadSlot): kill; dists vs live banks
        #pragma unroll
        for (int k = 0; k < 2; k++) {
            int s = bankSlot[wid * 2 + k];
            if (s == sb) {                                 // wave-uniform
                #pragma unroll
                for (int e = 0; e < 16; e++) R[k][e] = m[e];
            }
            if (s == deadSlot) {
                if (lane == 0) bankSlot[wid * 2 + k] = -1;
                s = -1;
            }
            if (s >= 0 && s != sb) {                       // wave-uniform
                double acc = 0.0;
                #pragma unroll
                for (int e = 0; e < 16; e++) {
                    float d = m[e] - R[k][e];
                    acc += (double)d * (double)d;
                }
                #pragma unroll
                for (int off = 32; off > 0; off >>= 1) acc += __shfl_down(acc, off, 64);
                if (lane == 0) { D[sb][s] = acc; D[s][sb] = acc; }
            }
        }
        __syncthreads();                                   // B3
        p ^= 1;
    }

    // final merged row is in m (all waves); wave 0 writes it
    if (wid == 0) {
        float4* od = (float4*)(out + (size_t)b * CDIM);
        #pragma unroll
        for (int q = 0; q < 4; q++)
            od[lane * 4 + q] = make_float4(m[4*q], m[4*q+1], m[4*q+2], m[4*q+3]);
    }
}

extern "C" void kernel_launch(void* const* d_in, const int* in_sizes, int n_in,
                              void* d_out, int out_size, void* d_ws, size_t ws_size,
                              hipStream_t stream) {
    const float* x  = (const float*)d_in[0]; // fp32 (512,32,1024)
    const float* w  = (const float*)d_in[1]; // fp32 (1,2,3)
    const float* cb = (const float*)d_in[2]; // fp32 (1,)
    float* out = (float*)d_out;              // fp32 (512,1024)
    (void)d_ws; (void)ws_size; (void)in_sizes; (void)n_in; (void)out_size;

    hipLaunchKernelGGL(merge_tree_kernel, dim3(BATCH), dim3(BDIM), 0, stream,
                       x, w, cb, out);
}

// Round 11
// 401.406 us; speedup vs baseline: 1.1861x; 1.1861x over previous
//
#include <hip/hip_runtime.h>
#include <stdint.h>

#define BDIM    1024                  // 16 waves per batch
#define NROWS   32
#define CDIM    1024
#define NSTEPS  31
#define BATCH   512

// One 1024-thread block (16 waves) per batch. ALL alive rows in REGISTERS:
// wave w owns 2 "banks" R[0..1] = slots 2w,2w+1; lane holds elements
// [lane*16 .. lane*16+15]. Merged row overwrites slot sb's bank and D-row
// (slot idx[bb] provably dead after every merge). The OTHER dead slot is
// idx[a] normally but idx[0] when a==1 (reference quirk: x[1] is both merged
// and survives at position bb; x[0] is dropped). Argmin DISTRIBUTED: one
// flat candidate per thread (n^2 <= 1024), per-wave butterfly -> 16 LDS
// partials -> every wave combines locally after B1 (same (fp64 d2, flat)
// lexicographic key = reference order). 3 barriers/step. No global reads
// after init.
// __launch_bounds__(1024,4): VGPR cap 128 — r10's (1024,8) forced VGPR=32
// and spilled R/m to scratch (61 MB writes, +300 MB fetches, 415 µs).
__global__ __launch_bounds__(BDIM, 4)
void merge_tree_kernel(const float* __restrict__ xin,  // B*32*1024 fp32
                       const float* __restrict__ wz,   // 6 fp32 (1,2,3)
                       const float* __restrict__ bz,   // 1 fp32
                       float* __restrict__ out)        // B*1024 fp32
{
    const int b    = blockIdx.x;
    const int tid  = threadIdx.x;
    const int lane = tid & 63;
    const int wid  = tid >> 6;        // 0..15

    const float* xb = xin + (size_t)b * NROWS * CDIM;

    __shared__ double D[NROWS][NROWS + 1];   // slot-indexed d2 (8448 B)
    __shared__ float  mA[16 * 64];           // conv partial (ch0), [e][lane]
    __shared__ float  mB[16 * 64];           // conv partial (ch1), [e][lane]
    __shared__ int    idxbuf[2][NROWS];      // logical pos -> slot
    __shared__ int    bankSlot[NROWS];       // bank (wid*2+k) -> slot, -1 dead
    __shared__ double wredv[16];             // per-wave argmin partial keys
    __shared__ int    wredp[16];             // per-wave argmin partial flats

    const float w00 = wz[0], w01 = wz[1], w02 = wz[2];
    const float w10 = wz[3], w11 = wz[4], w12 = wz[5];
    const float cb  = bz[0];

    float R[2][16];                   // 2 owned rows (32 VGPRs)
    float m[16];                      // current merged row / temp

    // ---------- load own rows (one-time) ----------
    #pragma unroll
    for (int k = 0; k < 2; k++) {
        const float4* src = (const float4*)(xb + (size_t)(2 * wid + k) * CDIM);
        #pragma unroll
        for (int q = 0; q < 4; q++) {
            float4 t = src[lane * 4 + q];
            R[k][4*q] = t.x; R[k][4*q+1] = t.y; R[k][4*q+2] = t.z; R[k][4*q+3] = t.w;
        }
    }
    if (tid < NROWS) { idxbuf[0][tid] = tid; bankSlot[tid] = tid; }

    // ---------- init pairwise D: stream row i, dist vs own banks ----------
    for (int i = 0; i < NROWS - 1; i++) {
        const float4* src = (const float4*)(xb + (size_t)i * CDIM);
        #pragma unroll
        for (int q = 0; q < 4; q++) {
            float4 t = src[lane * 4 + q];
            m[4*q] = t.x; m[4*q+1] = t.y; m[4*q+2] = t.z; m[4*q+3] = t.w;
        }
        // both banks' accumulators first (ILP), dual chains per bank
        double acc[2];
        #pragma unroll
        for (int k = 0; k < 2; k++) {
            double a0 = 0.0, a1 = 0.0;
            #pragma unroll
            for (int e = 0; e < 16; e += 2) {
                float d0 = m[e]     - R[k][e];
                float d1 = m[e + 1] - R[k][e + 1];
                a0 += (double)d0 * (double)d0;
                a1 += (double)d1 * (double)d1;
            }
            acc[k] = a0 + a1;
        }
        #pragma unroll
        for (int k = 0; k < 2; k++) {
            const int s = 2 * wid + k;
            if (s > i) {              // wave-uniform
                double av = acc[k];
                #pragma unroll
                for (int off = 32; off > 0; off >>= 1) av += __shfl_down(av, off, 64);
                if (lane == 0) { D[i][s] = av; D[s][i] = av; }
            }
        }
    }
    __syncthreads();

    // ---------- main merge loop: 3 barriers/step ----------
    int p = 0;
    for (int step = 0; step < NSTEPS; step++) {
        const int n = NROWS - step;
        int* idx  = idxbuf[p];
        int* nidx = idxbuf[p ^ 1];

        // --- argmin, distributed: one flat candidate per thread ---
        const uint32_t M = 0xFFFFFFFFu / (uint32_t)n + 1u;  // exact for flat<2^27
        {
            double bk = 1e300; int bp = 0x7fffffff;
            const int flat = tid;
            if (flat < n * n) {
                int i = (int)__umulhi((uint32_t)flat, M);
                int j = flat - i * n;
                if (j > i) { bk = D[idx[i]][idx[j]]; bp = flat; }
            }
            #pragma unroll
            for (int off = 1; off < 64; off <<= 1) {
                double ov = __shfl_xor(bk, off); int op = __shfl_xor(bp, off);
                if (ov < bk || (ov == bk && op < bp)) { bk = ov; bp = op; }
            }
            if (lane == 0) { wredv[wid] = bk; wredp[wid] = bp; }
        }
        __syncthreads();                                   // B1

        // combine 16 partials (every wave, redundant, no extra barrier)
        int a, bbj;
        {
            double v = (lane < 16) ? wredv[lane] : 1e300;
            int    q = (lane < 16) ? wredp[lane] : 0x7fffffff;
            #pragma unroll
            for (int off = 1; off < 16; off <<= 1) {
                double ov = __shfl_xor(v, off); int oq = __shfl_xor(q, off);
                if (ov < v || (ov == v && oq < q)) { v = ov; q = oq; }
            }
            const int best = __shfl(q, 0, 64);
            a   = (int)__umulhi((uint32_t)best, M);
            bbj = best - a * n;
        }
        const int sa = idx[a], sb = idx[bbj];
        // dead slots: sb (always) and idx[a] — except a==1 drops idx[0]
        const int deadSlot = (a == 1) ? idx[0] : sa;

        // --- conv partials by owner waves, from registers, into [e][lane] LDS ---
        #pragma unroll
        for (int k = 0; k < 2; k++) {
            const int s = bankSlot[wid * 2 + k];           // wave-uniform
            if (s == sa || s == sb) {
                float hl = __shfl_up(R[k][15], 1);  if (lane == 0)  hl = 0.0f;
                float hr = __shfl_down(R[k][0], 1); if (lane == 63) hr = 0.0f;
                float* dst = (s == sa) ? mA : mB;
                const float c0 = (s == sa) ? w00 : w10;
                const float c1 = (s == sa) ? w01 : w11;
                const float c2 = (s == sa) ? w02 : w12;
                #pragma unroll
                for (int e = 0; e < 16; e++) {
                    float xm1 = (e == 0)  ? hl : R[k][e - 1];
                    float xp1 = (e == 15) ? hr : R[k][e + 1];
                    dst[e * 64 + lane] = c0 * xm1 + c1 * R[k][e] + c2 * xp1;
                }
            }
        }
        // bookkeeping: new logical order (merged keeps slot id sb)
        if (tid == 0) nidx[0] = sb;
        if (tid >= 1 && tid < n - 1) {
            int kk = tid + 1;
            int src = (kk == bbj) ? 1 : ((kk == a) ? 0 : kk);
            nidx[tid] = idx[src];
        }
        __syncthreads();                                   // B2

        // --- finalize m (all waves); conflict-free strided reads ---
        #pragma unroll
        for (int e = 0; e < 16; e++) {
            float v = cb + mA[e * 64 + lane] + mB[e * 64 + lane];
            m[e] = v > 0.0f ? v : 0.0f;
        }
        // owner(sb): bank <- m; owner(deadSlot): kill; dists vs live banks
        int live[2];
        double acc[2];
        #pragma unroll
        for (int k = 0; k < 2; k++) {
            int s = bankSlot[wid * 2 + k];
            if (s == sb) {                                 // wave-uniform
                #pragma unroll
                for (int e = 0; e < 16; e++) R[k][e] = m[e];
            }
            if (s == deadSlot) {
                if (lane == 0) bankSlot[wid * 2 + k] = -1;
                s = -1;
            }
            live[k] = (s >= 0 && s != sb) ? s : -1;
            double a0 = 0.0, a1 = 0.0;
            if (live[k] >= 0) {                            // wave-uniform
                #pragma unroll
                for (int e = 0; e < 16; e += 2) {
                    float d0 = m[e]     - R[k][e];
                    float d1 = m[e + 1] - R[k][e + 1];
                    a0 += (double)d0 * (double)d0;
                    a1 += (double)d1 * (double)d1;
                }
            }
            acc[k] = a0 + a1;
        }
        #pragma unroll
        for (int k = 0; k < 2; k++) {
            if (live[k] >= 0) {                            // wave-uniform
                double av = acc[k];
                #pragma unroll
                for (int off = 32; off > 0; off >>= 1) av += __shfl_down(av, off, 64);
                if (lane == 0) { D[sb][live[k]] = av; D[live[k]][sb] = av; }
            }
        }
        __syncthreads();                                   // B3
        p ^= 1;
    }

    // final merged row is in m (all waves); wave 0 writes it
    if (wid == 0) {
        float4* od = (float4*)(out + (size_t)b * CDIM);
        #pragma unroll
        for (int q = 0; q < 4; q++)
            od[lane * 4 + q] = make_float4(m[4*q], m[4*q+1], m[4*q+2], m[4*q+3]);
    }
}

extern "C" void kernel_launch(void* const* d_in, const int* in_sizes, int n_in,
                              void* d_out, int out_size, void* d_ws, size_t ws_size,
                              hipStream_t stream) {
    const float* x  = (const float*)d_in[0]; // fp32 (512,32,1024)
    const float* w  = (const float*)d_in[1]; // fp32 (1,2,3)
    const float* cb = (const float*)d_in[2]; // fp32 (1,)
    float* out = (float*)d_out;              // fp32 (512,1024)
    (void)d_ws; (void)ws_size; (void)in_sizes; (void)n_in; (void)out_size;

    hipLaunchKernelGGL(merge_tree_kernel, dim3(BATCH), dim3(BDIM), 0, stream,
                       x, w, cb, out);
}